// Round 16
// baseline (136.424 us; speedup 1.0000x reference)
//
#include <hip/hip_runtime.h>
#include <math.h>

#define B 8
#define T 4
#define HID 2048
#define H 32
#define HKV 8
#define D 64
#define S 8192
#define ST (S + T)            // 8196
#define NREP (H / HKV)        // 4
#define EPS 1e-6f
#define SCALE 0.125f          // D^-0.5

#define SCB 256               // rows per attention block (4 sub-tiles)
#define NSUB 4
#define SUB 64                // rows per sub-tile
#define NCB 33                // chunk-blocks per bg (32 full + tail)
#define NCAT 3072             // concatenated qkv cols (2048 q | 512 k | 512 v)
#define KSPL 8                // K-split for projection GEMMs

typedef __attribute__((ext_vector_type(8))) _Float16 half8;
typedef __attribute__((ext_vector_type(4))) _Float16 half4;
typedef __attribute__((ext_vector_type(4))) float f32x4;

// LDS-only barrier: commits LDS ops, syncs workgroup, leaves vmcnt in flight.
#define LGKM_BARRIER()                                                   \
    do {                                                                 \
        asm volatile("s_waitcnt lgkmcnt(0)" ::: "memory");               \
        __builtin_amdgcn_s_barrier();                                    \
        __builtin_amdgcn_sched_barrier(0);                               \
    } while (0)

static __device__ __forceinline__ half8 cvt8(const float4 a, const float4 b) {
    half8 f;
    f[0] = (_Float16)a.x; f[1] = (_Float16)a.y; f[2] = (_Float16)a.z; f[3] = (_Float16)a.w;
    f[4] = (_Float16)b.x; f[5] = (_Float16)b.y; f[6] = (_Float16)b.z; f[7] = (_Float16)b.w;
    return f;
}
static __device__ __forceinline__ half4 cvt4v(const f32x4 a) {
    half4 f;
    f[0] = (_Float16)a[0]; f[1] = (_Float16)a[1]; f[2] = (_Float16)a[2]; f[3] = (_Float16)a[3];
    return f;
}

// ---------------- MFMA projection GEMM: part[ky][32][NCAT] = x @ [wq|wk|wv] ------
__global__ __launch_bounds__(256) void gemm_qkv_mfma(const float* __restrict__ x,
                                                     const float* __restrict__ wq,
                                                     const float* __restrict__ wk,
                                                     const float* __restrict__ wv,
                                                     float* __restrict__ part) {
    __shared__ __align__(16) _Float16 xs[32][136];
    __shared__ __align__(16) _Float16 wsl[32][136];   // transposed: [col][k]

    const int tid = threadIdx.x;
    const int lane = tid & 63;
    const int w = tid >> 6;
    const int q16 = lane & 15;
    const int kgrp = lane >> 4;
    const int tile = blockIdx.x;          // 0..95
    const int ky = blockIdx.y;            // 0..KSPL-1
    const int kbase = ky * (HID / KSPL);  // 256-slice

    const float* wsrc; int N, lcbase;
    if (tile < 64)      { wsrc = wq; N = 2048; lcbase = tile * 32; }
    else if (tile < 80) { wsrc = wk; N = 512;  lcbase = (tile - 64) * 32; }
    else                { wsrc = wv; N = 512;  lcbase = (tile - 80) * 32; }

    const int r0 = (w >> 1) * 16, c0 = (w & 1) * 16;
    f32x4 acc = {0.f, 0.f, 0.f, 0.f};

    for (int kc = 0; kc < 2; ++kc) {
        const int k0 = kbase + kc * 128;
#pragma unroll
        for (int i = 0; i < 4; ++i) {
            const int idx = tid + i * 256;            // 0..1023
            const int m = idx >> 5, slot = idx & 31;
            const f32x4 xv = *(const f32x4*)&x[(size_t)m * HID + k0 + slot * 4];
            *(half4*)&xs[m][slot * 4] = cvt4v(xv);
        }
#pragma unroll
        for (int i = 0; i < 4; ++i) {
            const int idx = tid + i * 256;            // 0..1023
            const int kk = idx >> 3, c4 = idx & 7;
            const f32x4 wv4 = *(const f32x4*)&wsrc[(size_t)(k0 + kk) * N + lcbase + c4 * 4];
            wsl[c4 * 4 + 0][kk] = (_Float16)wv4[0];
            wsl[c4 * 4 + 1][kk] = (_Float16)wv4[1];
            wsl[c4 * 4 + 2][kk] = (_Float16)wv4[2];
            wsl[c4 * 4 + 3][kk] = (_Float16)wv4[3];
        }
        __syncthreads();
#pragma unroll
        for (int ks = 0; ks < 4; ++ks) {
            const half8 af = *(const half8*)&xs[r0 + q16][ks * 32 + kgrp * 8];
            const half8 bf = *(const half8*)&wsl[c0 + q16][ks * 32 + kgrp * 8];
            acc = __builtin_amdgcn_mfma_f32_16x16x32_f16(af, bf, acc, 0, 0, 0);
        }
        __syncthreads();
    }

    const int gcol = tile * 32 + c0 + q16;
#pragma unroll
    for (int r = 0; r < 4; ++r) {
        const int m = r0 + kgrp * 4 + r;
        part[((size_t)ky * 32 + m) * NCAT + gcol] = acc[r];
    }
}

// ---------------- MFMA output GEMM: out += og @ wo (atomic over KSPL slices) -----
__global__ __launch_bounds__(256) void gemm_out_mfma(const float* __restrict__ og,
                                                     const float* __restrict__ wo,
                                                     float* __restrict__ out) {
    __shared__ __align__(16) _Float16 xs[32][136];
    __shared__ __align__(16) _Float16 wsl[32][136];

    const int tid = threadIdx.x;
    const int lane = tid & 63;
    const int w = tid >> 6;
    const int q16 = lane & 15;
    const int kgrp = lane >> 4;
    const int tile = blockIdx.x;          // 0..63
    const int ky = blockIdx.y;            // 0..KSPL-1
    const int kbase = ky * (HID / KSPL);
    const int lcbase = tile * 32;

    const int r0 = (w >> 1) * 16, c0 = (w & 1) * 16;
    f32x4 acc = {0.f, 0.f, 0.f, 0.f};

    for (int kc = 0; kc < 2; ++kc) {
        const int k0 = kbase + kc * 128;
#pragma unroll
        for (int i = 0; i < 4; ++i) {
            const int idx = tid + i * 256;
            const int m = idx >> 5, slot = idx & 31;
            const f32x4 xv = *(const f32x4*)&og[(size_t)m * 2048 + k0 + slot * 4];
            *(half4*)&xs[m][slot * 4] = cvt4v(xv);
        }
#pragma unroll
        for (int i = 0; i < 4; ++i) {
            const int idx = tid + i * 256;
            const int kk = idx >> 3, c4 = idx & 7;
            const f32x4 wv4 = *(const f32x4*)&wo[(size_t)(k0 + kk) * 2048 + lcbase + c4 * 4];
            wsl[c4 * 4 + 0][kk] = (_Float16)wv4[0];
            wsl[c4 * 4 + 1][kk] = (_Float16)wv4[1];
            wsl[c4 * 4 + 2][kk] = (_Float16)wv4[2];
            wsl[c4 * 4 + 3][kk] = (_Float16)wv4[3];
        }
        __syncthreads();
#pragma unroll
        for (int ks = 0; ks < 4; ++ks) {
            const half8 af = *(const half8*)&xs[r0 + q16][ks * 32 + kgrp * 8];
            const half8 bf = *(const half8*)&wsl[c0 + q16][ks * 32 + kgrp * 8];
            acc = __builtin_amdgcn_mfma_f32_16x16x32_f16(af, bf, acc, 0, 0, 0);
        }
        __syncthreads();
    }

    const int gcol = lcbase + c0 + q16;
#pragma unroll
    for (int r = 0; r < 4; ++r) {
        const int m = r0 + kgrp * 4 + r;
        atomicAdd(&out[(size_t)m * 2048 + gcol], acc[r]);
    }
}

// ---------------- rmsnorm + rope (sums the KSPL K-slice partials) ----------------
__global__ __launch_bounds__(256) void qkv_post(const float* __restrict__ part,
                                                const float* __restrict__ cosb,
                                                const float* __restrict__ sinb,
                                                const float* __restrict__ qnw,
                                                const float* __restrict__ knw,
                                                float* __restrict__ q_fin,
                                                float* __restrict__ kfull,
                                                float* __restrict__ vfull) {
    const int wid = (blockIdx.x * 256 + threadIdx.x) >> 6;
    const int lane = threadIdx.x & 63;
    if (wid < 1024) {
        const int m = wid >> 5, h = wid & 31;
        const size_t c = (size_t)m * NCAT + h * 64 + lane;
        float v = 0.f;
#pragma unroll
        for (int p = 0; p < KSPL; ++p) v += part[c + (size_t)p * 32 * NCAT];
        float ss = v * v;
#pragma unroll
        for (int off = 32; off; off >>= 1) ss += __shfl_xor(ss, off);
        float nv = qnw[lane] * v * rsqrtf(ss * (1.f / 64.f) + EPS);
        float other = __shfl_xor(nv, 32);
        float rot = (lane < 32) ? -other : other;
        float outv = nv * cosb[m * 64 + lane] + rot * sinb[m * 64 + lane];
        q_fin[(size_t)m * 2048 + h * 64 + lane] = outv * SCALE;
    } else if (wid < 1280) {
        const int idx = wid - 1024;
        const int m = idx >> 3, g = idx & 7;
        const size_t c = (size_t)m * NCAT + 2048 + g * 64 + lane;
        float v = 0.f;
#pragma unroll
        for (int p = 0; p < KSPL; ++p) v += part[c + (size_t)p * 32 * NCAT];
        float ss = v * v;
#pragma unroll
        for (int off = 32; off; off >>= 1) ss += __shfl_xor(ss, off);
        float nv = knw[lane] * v * rsqrtf(ss * (1.f / 64.f) + EPS);
        float other = __shfl_xor(nv, 32);
        float rot = (lane < 32) ? -other : other;
        float outv = nv * cosb[m * 64 + lane] + rot * sinb[m * 64 + lane];
        const int b = m >> 2, t = m & 3;
        kfull[((size_t)(b * HKV + g) * ST + S + t) * D + lane] = outv;
    } else if (wid < 1536) {
        const int idx = wid - 1280;
        const int m = idx >> 3, g = idx & 7;
        const size_t c = (size_t)m * NCAT + 2560 + g * 64 + lane;
        float v = 0.f;
#pragma unroll
        for (int p = 0; p < KSPL; ++p) v += part[c + (size_t)p * 32 * NCAT];
        const int b = m >> 2, t = m & 3;
        vfull[((size_t)(b * HKV + g) * ST + S + t) * D + lane] = v;
    }
}

// ---------------- fused cache-copy + attention partials ----------------
// Round-15 structure; ONLY change: kfull/vfull stores are normal (write-allocate
// L2) instead of nontemporal -- A/B test for the ~110MB WRITE_SIZE amplification.
__global__ __launch_bounds__(256, 5) void attn_part(const float* __restrict__ q_fin,
                                                    const float* __restrict__ ck,
                                                    const float* __restrict__ cv,
                                                    float* __restrict__ kfull,
                                                    float* __restrict__ vfull,
                                                    float* __restrict__ o_part,
                                                    float* __restrict__ ml_part) {
    const int bg = blockIdx.x;            // 0..63
    const int cb = blockIdx.y;            // 0..NCB-1
    const int b = bg >> 3, g = bg & 7;
    const int tid = threadIdx.x;
    const int lane = tid & 63;
    const int w = tid >> 6;               // wave 0..3
    const int q16 = lane & 15;
    const int kgrp = lane >> 4;           // 0..3

    __shared__ __align__(16) _Float16 kl[SUB][72];
    __shared__ __align__(16) _Float16 vl[SUB][72];
    __shared__ __align__(16) float scs[16][68];
    __shared__ __align__(16) _Float16 pb[16][72];
    __shared__ float Mrun[16], Lrun[16], srow[16];

    const bool full = (cb < 32);
    const int vm1 = full ? (SUB - 1) : (ST - S - 1);  // 63 or 3

    if (tid < 16) { Mrun[tid] = -3e38f; Lrun[tid] = 0.f; }

    half8 qf[2];
    {
        const float* qp = q_fin + ((size_t)(b * T + (q16 & 3)) * H + g * NREP + (q16 >> 2)) * D;
#pragma unroll
        for (int h = 0; h < 2; ++h) {
            const float* p = qp + h * 32 + kgrp * 8;
            qf[h] = cvt8(*(const float4*)p, *(const float4*)(p + 4));
        }
    }

    f32x4 oacc = {0.f, 0.f, 0.f, 0.f};
    const int dglob = w * 16 + q16;

    if (full) {
        const f32x4* ksrc = (const f32x4*)(ck + ((size_t)bg * S + (size_t)cb * SCB) * D);
        const f32x4* vsrc = (const f32x4*)(cv + ((size_t)bg * S + (size_t)cb * SCB) * D);
        f32x4* kdst = (f32x4*)(kfull + ((size_t)bg * ST + (size_t)cb * SCB) * D);
        f32x4* vdst = (f32x4*)(vfull + ((size_t)bg * ST + (size_t)cb * SCB) * D);

        f32x4 kr[4], vr[4];
#pragma unroll
        for (int i = 0; i < 4; ++i) {
            kr[i] = __builtin_nontemporal_load(&ksrc[tid + i * 256]);
            vr[i] = __builtin_nontemporal_load(&vsrc[tid + i * 256]);
        }

#pragma unroll
        for (int su = 0; su < NSUB; ++su) {
#pragma unroll
            for (int i = 0; i < 4; ++i) {
                const int idx = tid + i * 256;
                kdst[su * 1024 + idx] = kr[i];        // normal store (A/B vs NT)
                vdst[su * 1024 + idx] = vr[i];        // normal store (A/B vs NT)
                const int r = idx >> 4, cg = idx & 15;
                *(half4*)&kl[r][cg * 4] = cvt4v(kr[i]);
                *(half4*)&vl[r][cg * 4] = cvt4v(vr[i]);
            }
            if (su < NSUB - 1) {
#pragma unroll
                for (int i = 0; i < 4; ++i) {
                    kr[i] = __builtin_nontemporal_load(&ksrc[(su + 1) * 1024 + tid + i * 256]);
                    vr[i] = __builtin_nontemporal_load(&vsrc[(su + 1) * 1024 + tid + i * 256]);
                }
            }
            LGKM_BARRIER();

            {
                const int sl = w * 16 + q16;
                f32x4 acc = {0.f, 0.f, 0.f, 0.f};
#pragma unroll
                for (int h = 0; h < 2; ++h) {
                    const half8 kf = *(const half8*)&kl[sl][h * 32 + kgrp * 8];
                    acc = __builtin_amdgcn_mfma_f32_16x16x32_f16(kf, qf[h], acc, 0, 0, 0);
                }
                *(f32x4*)&scs[q16][w * 16 + kgrp * 4] = acc;
            }
            LGKM_BARRIER();

#pragma unroll
            for (int rr = 0; rr < 4; ++rr) {
                const int row = w * 4 + rr;
                const float v = scs[row][lane];
                float m_ = v;
#pragma unroll
                for (int off = 32; off; off >>= 1) m_ = fmaxf(m_, __shfl_xor(m_, off));
                const float Mold = Mrun[row];
                const float Mnew = fmaxf(Mold, m_);
                const float e = __expf(v - Mnew);
                float l = e;
#pragma unroll
                for (int off = 32; off; off >>= 1) l += __shfl_xor(l, off);
                pb[row][lane] = (_Float16)e;
                if (lane == 0) {
                    const float sc_ = __expf(Mold - Mnew);
                    srow[row] = sc_;
                    Lrun[row] = Lrun[row] * sc_ + l;
                    Mrun[row] = Mnew;
                }
            }
            LGKM_BARRIER();

            {
#pragma unroll
                for (int r = 0; r < 4; ++r) oacc[r] *= srow[kgrp * 4 + r];
#pragma unroll
                for (int ks = 0; ks < 2; ++ks) {
                    const half8 pa = *(const half8*)&pb[q16][ks * 32 + kgrp * 8];
                    half8 vf;
#pragma unroll
                    for (int e = 0; e < 8; ++e) {
                        vf[e] = vl[ks * 32 + kgrp * 8 + e][dglob];
                    }
                    oacc = __builtin_amdgcn_mfma_f32_16x16x32_f16(pa, vf, oacc, 0, 0, 0);
                }
            }
            LGKM_BARRIER();
        }
    } else {
        if (tid < 64) {
            const int r = tid >> 4, cg = tid & 15;
            const int rc = min(r, vm1);
            const f32x4 k4 = *(const f32x4*)(kfull + ((size_t)bg * ST + S + rc) * D + cg * 4);
            const f32x4 v4 = *(const f32x4*)(vfull + ((size_t)bg * ST + S + rc) * D + cg * 4);
            *(half4*)&kl[r][cg * 4] = cvt4v(k4);
            *(half4*)&vl[r][cg * 4] = cvt4v(v4);
        }
        __syncthreads();

        {
            const int sl = min(w * 16 + q16, vm1);
            f32x4 acc = {0.f, 0.f, 0.f, 0.f};
#pragma unroll
            for (int h = 0; h < 2; ++h) {
                const half8 kf = *(const half8*)&kl[sl][h * 32 + kgrp * 8];
                acc = __builtin_amdgcn_mfma_f32_16x16x32_f16(kf, qf[h], acc, 0, 0, 0);
            }
            const int sbase = w * 16 + kgrp * 4;
#pragma unroll
            for (int r = 0; r < 4; ++r)
                scs[q16][sbase + r] = (sbase + r <= vm1) ? acc[r] : -1e30f;
        }
        __syncthreads();

#pragma unroll
        for (int rr = 0; rr < 4; ++rr) {
            const int row = w * 4 + rr;
            const float v = scs[row][lane];
            float m_ = v;
#pragma unroll
            for (int off = 32; off; off >>= 1) m_ = fmaxf(m_, __shfl_xor(m_, off));
            const float Mnew = m_;
            const float e = __expf(v - Mnew);
            float l = e;
#pragma unroll
            for (int off = 32; off; off >>= 1) l += __shfl_xor(l, off);
            pb[row][lane] = (_Float16)e;
            if (lane == 0) { Lrun[row] = l; Mrun[row] = Mnew; }
        }
        __syncthreads();

        {
#pragma unroll
            for (int ks = 0; ks < 2; ++ks) {
                const half8 pa = *(const half8*)&pb[q16][ks * 32 + kgrp * 8];
                half8 vf;
#pragma unroll
                for (int e = 0; e < 8; ++e) {
                    const int sr = min(ks * 32 + kgrp * 8 + e, vm1);
                    vf[e] = vl[sr][dglob];
                }
                oacc = __builtin_amdgcn_mfma_f32_16x16x32_f16(pa, vf, oacc, 0, 0, 0);
            }
        }
        __syncthreads();
    }

#pragma unroll
    for (int r = 0; r < 4; ++r) {
        const int row = kgrp * 4 + r;
        o_part[(((size_t)bg * 16 + row) * NCB + cb) * 64 + dglob] = oacc[r];
    }
    if (tid < 16) {
        ml_part[(((size_t)bg * 16 + tid) * NCB + cb) * 2 + 0] = Mrun[tid];
        ml_part[(((size_t)bg * 16 + tid) * NCB + cb) * 2 + 1] = Lrun[tid];
    }
}

// ---------------- combine partials (+ zero `out` for the atomic out-proj) --------
__global__ __launch_bounds__(256) void attn_combine(const float* __restrict__ o_part,
                                                    const float* __restrict__ ml_part,
                                                    float* __restrict__ og,
                                                    float* __restrict__ out) {
    out[blockIdx.x * 256 + threadIdx.x] = 0.f;   // 256*256 == 32*2048

    const int gw = (blockIdx.x * 256 + threadIdx.x) >> 6;  // 0..1023
    const int lane = threadIdx.x & 63;
    const int bg = gw >> 4, row = gw & 15;
    float M = -1e30f, L = 0.f, O = 0.f;
    for (int c = 0; c < NCB; ++c) {
        const float m_ = ml_part[((size_t)gw * NCB + c) * 2 + 0];
        const float l_ = ml_part[((size_t)gw * NCB + c) * 2 + 1];
        const float o_ = o_part[((size_t)gw * NCB + c) * 64 + lane];
        const float Mn = fmaxf(M, m_);
        const float fa = __expf(M - Mn), fb = __expf(m_ - Mn);
        O = O * fa + o_ * fb;
        L = L * fa + l_ * fb;
        M = Mn;
    }
    const float o = O / L;
    const int b = bg >> 3, g = bg & 7, r = row >> 2, t = row & 3;
    og[((size_t)(b * T + t) * H + (g * NREP + r)) * D + lane] = o;
}

extern "C" void kernel_launch(void* const* d_in, const int* in_sizes, int n_in,
                              void* d_out, int out_size, void* d_ws, size_t ws_size,
                              hipStream_t stream) {
    const float* x    = (const float*)d_in[0];
    const float* cosb = (const float*)d_in[1];
    const float* sinb = (const float*)d_in[2];
    const float* ck   = (const float*)d_in[3];
    const float* cv   = (const float*)d_in[4];
    const float* wq   = (const float*)d_in[5];
    const float* wk   = (const float*)d_in[6];
    const float* wvp  = (const float*)d_in[7];
    const float* wo   = (const float*)d_in[8];
    const float* qnw  = (const float*)d_in[9];
    const float* knw  = (const float*)d_in[10];

    float* out   = (float*)d_out;                       // [32][2048]
    float* kfull = out + 65536;                         // [B][HKV][ST][D]
    float* vfull = kfull + (size_t)B * HKV * ST * D;

    float* ws      = (float*)d_ws;
    float* qkvp    = ws;                                  // [KSPL][32][3072]
    float* q_fin   = qkvp + (size_t)KSPL * 32 * NCAT;     // 65536
    float* og      = q_fin + 65536;                       // 65536
    float* o_part  = og + 65536;                          // 64*16*NCB*64
    float* ml_part = o_part + (size_t)64 * 16 * NCB * 64;

    // qkv projections (MFMA, K split over KSPL partial buffers)
    gemm_qkv_mfma<<<dim3(96, KSPL), 256, 0, stream>>>(x, wq, wk, wvp, qkvp);

    // rmsnorm + rope (sums partials), scatter new K/V rows
    qkv_post<<<384, 256, 0, stream>>>(qkvp, cosb, sinb, qnw, knw, q_fin, kfull, vfull);

    // fused cache-copy + attention partials
    attn_part<<<dim3(64, NCB), 256, 0, stream>>>(q_fin, ck, cv, kfull, vfull, o_part, ml_part);

    // combine (also zeroes `out` ahead of the atomic out-projection)
    attn_combine<<<256, 256, 0, stream>>>(o_part, ml_part, og, out);

    // output projection (MFMA, KSPL K-slices accumulate atomically)
    gemm_out_mfma<<<dim3(64, KSPL), 256, 0, stream>>>(og, wo, out);
}

// Round 17
// 131.630 us; speedup vs baseline: 1.0364x; 1.0364x over previous
//
#include <hip/hip_runtime.h>
#include <math.h>

#define B 8
#define T 4
#define HID 2048
#define H 32
#define HKV 8
#define D 64
#define S 8192
#define ST (S + T)            // 8196
#define NREP (H / HKV)        // 4
#define EPS 1e-6f
#define SCALE 0.125f          // D^-0.5

#define SCB 256               // rows per attention block (4 sub-tiles)
#define NSUB 4
#define SUB 64                // rows per sub-tile
#define NCB 33                // chunk-blocks per bg (32 full + tail)
#define NCAT 3072             // concatenated qkv cols (2048 q | 512 k | 512 v)
#define KSPL 8                // K-split for projection GEMMs

typedef __attribute__((ext_vector_type(8))) _Float16 half8;
typedef __attribute__((ext_vector_type(4))) _Float16 half4;
typedef __attribute__((ext_vector_type(4))) float f32x4;

// LDS-only barrier: commits LDS ops, syncs workgroup, leaves vmcnt in flight.
#define LGKM_BARRIER()                                                   \
    do {                                                                 \
        asm volatile("s_waitcnt lgkmcnt(0)" ::: "memory");               \
        __builtin_amdgcn_s_barrier();                                    \
        __builtin_amdgcn_sched_barrier(0);                               \
    } while (0)

static __device__ __forceinline__ half8 cvt8(const float4 a, const float4 b) {
    half8 f;
    f[0] = (_Float16)a.x; f[1] = (_Float16)a.y; f[2] = (_Float16)a.z; f[3] = (_Float16)a.w;
    f[4] = (_Float16)b.x; f[5] = (_Float16)b.y; f[6] = (_Float16)b.z; f[7] = (_Float16)b.w;
    return f;
}
static __device__ __forceinline__ half4 cvt4v(const f32x4 a) {
    half4 f;
    f[0] = (_Float16)a[0]; f[1] = (_Float16)a[1]; f[2] = (_Float16)a[2]; f[3] = (_Float16)a[3];
    return f;
}

// ---------------- MFMA projection GEMM: part[ky][32][NCAT] = x @ [wq|wk|wv] ------
__global__ __launch_bounds__(256) void gemm_qkv_mfma(const float* __restrict__ x,
                                                     const float* __restrict__ wq,
                                                     const float* __restrict__ wk,
                                                     const float* __restrict__ wv,
                                                     float* __restrict__ part) {
    __shared__ __align__(16) _Float16 xs[32][136];
    __shared__ __align__(16) _Float16 wsl[32][136];   // transposed: [col][k]

    const int tid = threadIdx.x;
    const int lane = tid & 63;
    const int w = tid >> 6;
    const int q16 = lane & 15;
    const int kgrp = lane >> 4;
    const int tile = blockIdx.x;          // 0..95
    const int ky = blockIdx.y;            // 0..KSPL-1
    const int kbase = ky * (HID / KSPL);  // 256-slice

    const float* wsrc; int N, lcbase;
    if (tile < 64)      { wsrc = wq; N = 2048; lcbase = tile * 32; }
    else if (tile < 80) { wsrc = wk; N = 512;  lcbase = (tile - 64) * 32; }
    else                { wsrc = wv; N = 512;  lcbase = (tile - 80) * 32; }

    const int r0 = (w >> 1) * 16, c0 = (w & 1) * 16;
    f32x4 acc = {0.f, 0.f, 0.f, 0.f};

    for (int kc = 0; kc < 2; ++kc) {
        const int k0 = kbase + kc * 128;
#pragma unroll
        for (int i = 0; i < 4; ++i) {
            const int idx = tid + i * 256;            // 0..1023
            const int m = idx >> 5, slot = idx & 31;
            const f32x4 xv = *(const f32x4*)&x[(size_t)m * HID + k0 + slot * 4];
            *(half4*)&xs[m][slot * 4] = cvt4v(xv);
        }
#pragma unroll
        for (int i = 0; i < 4; ++i) {
            const int idx = tid + i * 256;            // 0..1023
            const int kk = idx >> 3, c4 = idx & 7;
            const f32x4 wv4 = *(const f32x4*)&wsrc[(size_t)(k0 + kk) * N + lcbase + c4 * 4];
            wsl[c4 * 4 + 0][kk] = (_Float16)wv4[0];
            wsl[c4 * 4 + 1][kk] = (_Float16)wv4[1];
            wsl[c4 * 4 + 2][kk] = (_Float16)wv4[2];
            wsl[c4 * 4 + 3][kk] = (_Float16)wv4[3];
        }
        __syncthreads();
#pragma unroll
        for (int ks = 0; ks < 4; ++ks) {
            const half8 af = *(const half8*)&xs[r0 + q16][ks * 32 + kgrp * 8];
            const half8 bf = *(const half8*)&wsl[c0 + q16][ks * 32 + kgrp * 8];
            acc = __builtin_amdgcn_mfma_f32_16x16x32_f16(af, bf, acc, 0, 0, 0);
        }
        __syncthreads();
    }

    const int gcol = tile * 32 + c0 + q16;
#pragma unroll
    for (int r = 0; r < 4; ++r) {
        const int m = r0 + kgrp * 4 + r;
        part[((size_t)ky * 32 + m) * NCAT + gcol] = acc[r];
    }
}

// ---------------- MFMA output GEMM: out += og @ wo (atomic over KSPL slices) -----
__global__ __launch_bounds__(256) void gemm_out_mfma(const float* __restrict__ og,
                                                     const float* __restrict__ wo,
                                                     float* __restrict__ out) {
    __shared__ __align__(16) _Float16 xs[32][136];
    __shared__ __align__(16) _Float16 wsl[32][136];

    const int tid = threadIdx.x;
    const int lane = tid & 63;
    const int w = tid >> 6;
    const int q16 = lane & 15;
    const int kgrp = lane >> 4;
    const int tile = blockIdx.x;          // 0..63
    const int ky = blockIdx.y;            // 0..KSPL-1
    const int kbase = ky * (HID / KSPL);
    const int lcbase = tile * 32;

    const int r0 = (w >> 1) * 16, c0 = (w & 1) * 16;
    f32x4 acc = {0.f, 0.f, 0.f, 0.f};

    for (int kc = 0; kc < 2; ++kc) {
        const int k0 = kbase + kc * 128;
#pragma unroll
        for (int i = 0; i < 4; ++i) {
            const int idx = tid + i * 256;
            const int m = idx >> 5, slot = idx & 31;
            const f32x4 xv = *(const f32x4*)&og[(size_t)m * 2048 + k0 + slot * 4];
            *(half4*)&xs[m][slot * 4] = cvt4v(xv);
        }
#pragma unroll
        for (int i = 0; i < 4; ++i) {
            const int idx = tid + i * 256;
            const int kk = idx >> 3, c4 = idx & 7;
            const f32x4 wv4 = *(const f32x4*)&wo[(size_t)(k0 + kk) * 2048 + lcbase + c4 * 4];
            wsl[c4 * 4 + 0][kk] = (_Float16)wv4[0];
            wsl[c4 * 4 + 1][kk] = (_Float16)wv4[1];
            wsl[c4 * 4 + 2][kk] = (_Float16)wv4[2];
            wsl[c4 * 4 + 3][kk] = (_Float16)wv4[3];
        }
        __syncthreads();
#pragma unroll
        for (int ks = 0; ks < 4; ++ks) {
            const half8 af = *(const half8*)&xs[r0 + q16][ks * 32 + kgrp * 8];
            const half8 bf = *(const half8*)&wsl[c0 + q16][ks * 32 + kgrp * 8];
            acc = __builtin_amdgcn_mfma_f32_16x16x32_f16(af, bf, acc, 0, 0, 0);
        }
        __syncthreads();
    }

    const int gcol = lcbase + c0 + q16;
#pragma unroll
    for (int r = 0; r < 4; ++r) {
        const int m = r0 + kgrp * 4 + r;
        atomicAdd(&out[(size_t)m * 2048 + gcol], acc[r]);
    }
}

// ---------------- rmsnorm + rope (sums the KSPL K-slice partials) ----------------
__global__ __launch_bounds__(256) void qkv_post(const float* __restrict__ part,
                                                const float* __restrict__ cosb,
                                                const float* __restrict__ sinb,
                                                const float* __restrict__ qnw,
                                                const float* __restrict__ knw,
                                                float* __restrict__ q_fin,
                                                float* __restrict__ kfull,
                                                float* __restrict__ vfull) {
    const int wid = (blockIdx.x * 256 + threadIdx.x) >> 6;
    const int lane = threadIdx.x & 63;
    if (wid < 1024) {
        const int m = wid >> 5, h = wid & 31;
        const size_t c = (size_t)m * NCAT + h * 64 + lane;
        float v = 0.f;
#pragma unroll
        for (int p = 0; p < KSPL; ++p) v += part[c + (size_t)p * 32 * NCAT];
        float ss = v * v;
#pragma unroll
        for (int off = 32; off; off >>= 1) ss += __shfl_xor(ss, off);
        float nv = qnw[lane] * v * rsqrtf(ss * (1.f / 64.f) + EPS);
        float other = __shfl_xor(nv, 32);
        float rot = (lane < 32) ? -other : other;
        float outv = nv * cosb[m * 64 + lane] + rot * sinb[m * 64 + lane];
        q_fin[(size_t)m * 2048 + h * 64 + lane] = outv * SCALE;
    } else if (wid < 1280) {
        const int idx = wid - 1024;
        const int m = idx >> 3, g = idx & 7;
        const size_t c = (size_t)m * NCAT + 2048 + g * 64 + lane;
        float v = 0.f;
#pragma unroll
        for (int p = 0; p < KSPL; ++p) v += part[c + (size_t)p * 32 * NCAT];
        float ss = v * v;
#pragma unroll
        for (int off = 32; off; off >>= 1) ss += __shfl_xor(ss, off);
        float nv = knw[lane] * v * rsqrtf(ss * (1.f / 64.f) + EPS);
        float other = __shfl_xor(nv, 32);
        float rot = (lane < 32) ? -other : other;
        float outv = nv * cosb[m * 64 + lane] + rot * sinb[m * 64 + lane];
        const int b = m >> 2, t = m & 3;
        kfull[((size_t)(b * HKV + g) * ST + S + t) * D + lane] = outv;
    } else if (wid < 1536) {
        const int idx = wid - 1280;
        const int m = idx >> 3, g = idx & 7;
        const size_t c = (size_t)m * NCAT + 2560 + g * 64 + lane;
        float v = 0.f;
#pragma unroll
        for (int p = 0; p < KSPL; ++p) v += part[c + (size_t)p * 32 * NCAT];
        const int b = m >> 2, t = m & 3;
        vfull[((size_t)(b * HKV + g) * ST + S + t) * D + lane] = v;
    }
}

// ---------------- fused cache-copy + attention partials (best config: round 15) --
__global__ __launch_bounds__(256, 5) void attn_part(const float* __restrict__ q_fin,
                                                    const float* __restrict__ ck,
                                                    const float* __restrict__ cv,
                                                    float* __restrict__ kfull,
                                                    float* __restrict__ vfull,
                                                    float* __restrict__ o_part,
                                                    float* __restrict__ ml_part) {
    const int bg = blockIdx.x;            // 0..63
    const int cb = blockIdx.y;            // 0..NCB-1
    const int b = bg >> 3, g = bg & 7;
    const int tid = threadIdx.x;
    const int lane = tid & 63;
    const int w = tid >> 6;               // wave 0..3
    const int q16 = lane & 15;
    const int kgrp = lane >> 4;           // 0..3

    __shared__ __align__(16) _Float16 kl[SUB][72];
    __shared__ __align__(16) _Float16 vl[SUB][72];
    __shared__ __align__(16) float scs[16][68];
    __shared__ __align__(16) _Float16 pb[16][72];
    __shared__ float Mrun[16], Lrun[16], srow[16];

    const bool full = (cb < 32);
    const int vm1 = full ? (SUB - 1) : (ST - S - 1);  // 63 or 3

    if (tid < 16) { Mrun[tid] = -3e38f; Lrun[tid] = 0.f; }

    half8 qf[2];
    {
        const float* qp = q_fin + ((size_t)(b * T + (q16 & 3)) * H + g * NREP + (q16 >> 2)) * D;
#pragma unroll
        for (int h = 0; h < 2; ++h) {
            const float* p = qp + h * 32 + kgrp * 8;
            qf[h] = cvt8(*(const float4*)p, *(const float4*)(p + 4));
        }
    }

    f32x4 oacc = {0.f, 0.f, 0.f, 0.f};
    const int dglob = w * 16 + q16;

    if (full) {
        const f32x4* ksrc = (const f32x4*)(ck + ((size_t)bg * S + (size_t)cb * SCB) * D);
        const f32x4* vsrc = (const f32x4*)(cv + ((size_t)bg * S + (size_t)cb * SCB) * D);
        f32x4* kdst = (f32x4*)(kfull + ((size_t)bg * ST + (size_t)cb * SCB) * D);
        f32x4* vdst = (f32x4*)(vfull + ((size_t)bg * ST + (size_t)cb * SCB) * D);

        f32x4 kr[4], vr[4];
#pragma unroll
        for (int i = 0; i < 4; ++i) {
            kr[i] = __builtin_nontemporal_load(&ksrc[tid + i * 256]);
            vr[i] = __builtin_nontemporal_load(&vsrc[tid + i * 256]);
        }

#pragma unroll
        for (int su = 0; su < NSUB; ++su) {
#pragma unroll
            for (int i = 0; i < 4; ++i) {
                const int idx = tid + i * 256;
                __builtin_nontemporal_store(kr[i], &kdst[su * 1024 + idx]);
                __builtin_nontemporal_store(vr[i], &vdst[su * 1024 + idx]);
                const int r = idx >> 4, cg = idx & 15;
                *(half4*)&kl[r][cg * 4] = cvt4v(kr[i]);
                *(half4*)&vl[r][cg * 4] = cvt4v(vr[i]);
            }
            if (su < NSUB - 1) {
#pragma unroll
                for (int i = 0; i < 4; ++i) {
                    kr[i] = __builtin_nontemporal_load(&ksrc[(su + 1) * 1024 + tid + i * 256]);
                    vr[i] = __builtin_nontemporal_load(&vsrc[(su + 1) * 1024 + tid + i * 256]);
                }
            }
            LGKM_BARRIER();

            {
                const int sl = w * 16 + q16;
                f32x4 acc = {0.f, 0.f, 0.f, 0.f};
#pragma unroll
                for (int h = 0; h < 2; ++h) {
                    const half8 kf = *(const half8*)&kl[sl][h * 32 + kgrp * 8];
                    acc = __builtin_amdgcn_mfma_f32_16x16x32_f16(kf, qf[h], acc, 0, 0, 0);
                }
                *(f32x4*)&scs[q16][w * 16 + kgrp * 4] = acc;
            }
            LGKM_BARRIER();

#pragma unroll
            for (int rr = 0; rr < 4; ++rr) {
                const int row = w * 4 + rr;
                const float v = scs[row][lane];
                float m_ = v;
#pragma unroll
                for (int off = 32; off; off >>= 1) m_ = fmaxf(m_, __shfl_xor(m_, off));
                const float Mold = Mrun[row];
                const float Mnew = fmaxf(Mold, m_);
                const float e = __expf(v - Mnew);
                float l = e;
#pragma unroll
                for (int off = 32; off; off >>= 1) l += __shfl_xor(l, off);
                pb[row][lane] = (_Float16)e;
                if (lane == 0) {
                    const float sc_ = __expf(Mold - Mnew);
                    srow[row] = sc_;
                    Lrun[row] = Lrun[row] * sc_ + l;
                    Mrun[row] = Mnew;
                }
            }
            LGKM_BARRIER();

            {
#pragma unroll
                for (int r = 0; r < 4; ++r) oacc[r] *= srow[kgrp * 4 + r];
#pragma unroll
                for (int ks = 0; ks < 2; ++ks) {
                    const half8 pa = *(const half8*)&pb[q16][ks * 32 + kgrp * 8];
                    half8 vf;
#pragma unroll
                    for (int e = 0; e < 8; ++e) {
                        vf[e] = vl[ks * 32 + kgrp * 8 + e][dglob];
                    }
                    oacc = __builtin_amdgcn_mfma_f32_16x16x32_f16(pa, vf, oacc, 0, 0, 0);
                }
            }
            LGKM_BARRIER();
        }
    } else {
        if (tid < 64) {
            const int r = tid >> 4, cg = tid & 15;
            const int rc = min(r, vm1);
            const f32x4 k4 = *(const f32x4*)(kfull + ((size_t)bg * ST + S + rc) * D + cg * 4);
            const f32x4 v4 = *(const f32x4*)(vfull + ((size_t)bg * ST + S + rc) * D + cg * 4);
            *(half4*)&kl[r][cg * 4] = cvt4v(k4);
            *(half4*)&vl[r][cg * 4] = cvt4v(v4);
        }
        __syncthreads();

        {
            const int sl = min(w * 16 + q16, vm1);
            f32x4 acc = {0.f, 0.f, 0.f, 0.f};
#pragma unroll
            for (int h = 0; h < 2; ++h) {
                const half8 kf = *(const half8*)&kl[sl][h * 32 + kgrp * 8];
                acc = __builtin_amdgcn_mfma_f32_16x16x32_f16(kf, qf[h], acc, 0, 0, 0);
            }
            const int sbase = w * 16 + kgrp * 4;
#pragma unroll
            for (int r = 0; r < 4; ++r)
                scs[q16][sbase + r] = (sbase + r <= vm1) ? acc[r] : -1e30f;
        }
        __syncthreads();

#pragma unroll
        for (int rr = 0; rr < 4; ++rr) {
            const int row = w * 4 + rr;
            const float v = scs[row][lane];
            float m_ = v;
#pragma unroll
            for (int off = 32; off; off >>= 1) m_ = fmaxf(m_, __shfl_xor(m_, off));
            const float Mnew = m_;
            const float e = __expf(v - Mnew);
            float l = e;
#pragma unroll
            for (int off = 32; off; off >>= 1) l += __shfl_xor(l, off);
            pb[row][lane] = (_Float16)e;
            if (lane == 0) { Lrun[row] = l; Mrun[row] = Mnew; }
        }
        __syncthreads();

        {
#pragma unroll
            for (int ks = 0; ks < 2; ++ks) {
                const half8 pa = *(const half8*)&pb[q16][ks * 32 + kgrp * 8];
                half8 vf;
#pragma unroll
                for (int e = 0; e < 8; ++e) {
                    const int sr = min(ks * 32 + kgrp * 8 + e, vm1);
                    vf[e] = vl[sr][dglob];
                }
                oacc = __builtin_amdgcn_mfma_f32_16x16x32_f16(pa, vf, oacc, 0, 0, 0);
            }
        }
        __syncthreads();
    }

#pragma unroll
    for (int r = 0; r < 4; ++r) {
        const int row = kgrp * 4 + r;
        o_part[(((size_t)bg * 16 + row) * NCB + cb) * 64 + dglob] = oacc[r];
    }
    if (tid < 16) {
        ml_part[(((size_t)bg * 16 + tid) * NCB + cb) * 2 + 0] = Mrun[tid];
        ml_part[(((size_t)bg * 16 + tid) * NCB + cb) * 2 + 1] = Lrun[tid];
    }
}

// ---------------- combine partials (+ zero `out` for the atomic out-proj) --------
__global__ __launch_bounds__(256) void attn_combine(const float* __restrict__ o_part,
                                                    const float* __restrict__ ml_part,
                                                    float* __restrict__ og,
                                                    float* __restrict__ out) {
    out[blockIdx.x * 256 + threadIdx.x] = 0.f;   // 256*256 == 32*2048

    const int gw = (blockIdx.x * 256 + threadIdx.x) >> 6;  // 0..1023
    const int lane = threadIdx.x & 63;
    const int bg = gw >> 4, row = gw & 15;
    float M = -1e30f, L = 0.f, O = 0.f;
    for (int c = 0; c < NCB; ++c) {
        const float m_ = ml_part[((size_t)gw * NCB + c) * 2 + 0];
        const float l_ = ml_part[((size_t)gw * NCB + c) * 2 + 1];
        const float o_ = o_part[((size_t)gw * NCB + c) * 64 + lane];
        const float Mn = fmaxf(M, m_);
        const float fa = __expf(M - Mn), fb = __expf(m_ - Mn);
        O = O * fa + o_ * fb;
        L = L * fa + l_ * fb;
        M = Mn;
    }
    const float o = O / L;
    const int b = bg >> 3, g = bg & 7, r = row >> 2, t = row & 3;
    og[((size_t)(b * T + t) * H + (g * NREP + r)) * D + lane] = o;
}

extern "C" void kernel_launch(void* const* d_in, const int* in_sizes, int n_in,
                              void* d_out, int out_size, void* d_ws, size_t ws_size,
                              hipStream_t stream) {
    const float* x    = (const float*)d_in[0];
    const float* cosb = (const float*)d_in[1];
    const float* sinb = (const float*)d_in[2];
    const float* ck   = (const float*)d_in[3];
    const float* cv   = (const float*)d_in[4];
    const float* wq   = (const float*)d_in[5];
    const float* wk   = (const float*)d_in[6];
    const float* wvp  = (const float*)d_in[7];
    const float* wo   = (const float*)d_in[8];
    const float* qnw  = (const float*)d_in[9];
    const float* knw  = (const float*)d_in[10];

    float* out   = (float*)d_out;                       // [32][2048]
    float* kfull = out + 65536;                         // [B][HKV][ST][D]
    float* vfull = kfull + (size_t)B * HKV * ST * D;

    float* ws      = (float*)d_ws;
    float* qkvp    = ws;                                  // [KSPL][32][3072]
    float* q_fin   = qkvp + (size_t)KSPL * 32 * NCAT;     // 65536
    float* og      = q_fin + 65536;                       // 65536
    float* o_part  = og + 65536;                          // 64*16*NCB*64
    float* ml_part = o_part + (size_t)64 * 16 * NCB * 64;

    // qkv projections (MFMA, K split over KSPL partial buffers)
    gemm_qkv_mfma<<<dim3(96, KSPL), 256, 0, stream>>>(x, wq, wk, wvp, qkvp);

    // rmsnorm + rope (sums partials), scatter new K/V rows
    qkv_post<<<384, 256, 0, stream>>>(qkvp, cosb, sinb, qnw, knw, q_fin, kfull, vfull);

    // fused cache-copy + attention partials
    attn_part<<<dim3(64, NCB), 256, 0, stream>>>(q_fin, ck, cv, kfull, vfull, o_part, ml_part);

    // combine (also zeroes `out` ahead of the atomic out-projection)
    attn_combine<<<256, 256, 0, stream>>>(o_part, ml_part, og, out);

    // output projection (MFMA, KSPL K-slices accumulate atomically)
    gemm_out_mfma<<<dim3(64, KSPL), 256, 0, stream>>>(og, wo, out);
}